// Round 5
// baseline (719.239 us; speedup 1.0000x reference)
//
#include <hip/hip_runtime.h>
#include <hip/hip_cooperative_groups.h>
#include <math.h>

namespace cg = cooperative_groups;

// OFPenalty round 5: persistent cooperative kernel, sized so the launch
// CANNOT be rejected: 256 blocks (1/CU) x 1024 threads. Round 4's 1024-block
// version never ran (silent hipErrorCooperativeLaunchTooLarge -> out==0).
// Fallback to the proven round-3 multi-launch path if coop launch fails.
// Pipeline: 6 double-matvecs v = W(W^T x_hat) per batch, AAT never formed.
// A: (64, 512, 28, 28) fp32 -> W: (64, 512, 784). x0: (64, 512, 1).

#define BB 64
#define CC 512
#define DD 784
#define FEPS 1e-12f

// ---- cooperative version: 256 blocks x 1024 thr, block = (b, 128-row stripe)
#define NBLK 256
#define TPB  1024
#define RPB  128          // rows per block (512 / 4 stripes)

__device__ __forceinline__ float blk_reduce16(float s, float* red) {
    for (int off = 32; off; off >>= 1) s += __shfl_down(s, off, 64);
    int w = threadIdx.x >> 6;
    if ((threadIdx.x & 63) == 0) red[w] = s;
    __syncthreads();
    float t = 0.0f;
#pragma unroll
    for (int i = 0; i < 16; i++) t += red[i];
    __syncthreads();
    return t;
}

__device__ __forceinline__ float ss512c(const float* __restrict__ p, float* red) {
    float v = (threadIdx.x < CC) ? p[threadIdx.x] : 0.0f;
    return blk_reduce16(v * v, red);
}

// u_b += sum over this block's 128 rows of A[c,:] * (x_b[c] * rn)
__device__ void c_phase_u(const float* __restrict__ Ab, const float* __restrict__ xb,
                          float rn, float* __restrict__ ub, int c0,
                          float (*up)[800]) {
    int wave = threadIdx.x >> 6, lane = threadIdx.x & 63;
    float xv[8];
#pragma unroll
    for (int i = 0; i < 8; i++) xv[i] = xb[c0 + wave + 16 * i] * rn;
    const float4* Abase = (const float4*)(Ab + (size_t)c0 * DD);
    float4 a0 = make_float4(0.f,0.f,0.f,0.f), a1 = a0, a2 = a0, a3 = a0;
#pragma unroll 2
    for (int i = 0; i < 8; i++) {
        const float4* row = Abase + (size_t)(wave + 16 * i) * 196;  // 784/4
        float xc = xv[i];
        float4 f0 = row[lane], f1 = row[lane + 64], f2 = row[lane + 128];
        a0.x += f0.x*xc; a0.y += f0.y*xc; a0.z += f0.z*xc; a0.w += f0.w*xc;
        a1.x += f1.x*xc; a1.y += f1.y*xc; a1.z += f1.z*xc; a1.w += f1.w*xc;
        a2.x += f2.x*xc; a2.y += f2.y*xc; a2.z += f2.z*xc; a2.w += f2.w*xc;
        if (lane < 4) {
            float4 f3 = row[192 + lane];
            a3.x += f3.x*xc; a3.y += f3.y*xc; a3.z += f3.z*xc; a3.w += f3.w*xc;
        }
    }
    int d4 = 4 * lane;
    *(float4*)&up[wave][d4]       = a0;
    *(float4*)&up[wave][d4 + 256] = a1;
    *(float4*)&up[wave][d4 + 512] = a2;
    if (lane < 4) *(float4*)&up[wave][d4 + 768] = a3;
    __syncthreads();
    int d = threadIdx.x;
    if (d < DD) {
        float s = 0.0f;
#pragma unroll
        for (int w = 0; w < 16; w++) s += up[w][d];
        atomicAdd(&ub[d], s);
    }
    __syncthreads();
}

// v_b[c] = <A[c,:], u_b> for this block's 128 rows (wave per row).
// mode 1: also accumulate dotwx += v*xn, den2 += xn^2, xn = x2b[c]*rn2.
__device__ void c_phase_v(const float* __restrict__ Ab, const float* __restrict__ ub,
                          float* __restrict__ vb, int c0, int mode,
                          float* slot0, float* slot1,
                          const float* __restrict__ x2b, float rn2) {
    int wave = threadIdx.x >> 6, lane = threadIdx.x & 63;
    const float4* up4 = (const float4*)ub;
    float4 u0 = up4[lane], u1 = up4[lane + 64], u2 = up4[lane + 128];
    float4 u3 = make_float4(0.f,0.f,0.f,0.f);
    if (lane < 4) u3 = up4[192 + lane];
    float p0 = 0.0f, p1 = 0.0f;
#pragma unroll 2
    for (int j = 0; j < 8; j++) {
        int c = c0 + wave * 8 + j;
        const float4* row = (const float4*)(Ab + (size_t)c * DD);
        float4 f0 = row[lane], f1 = row[lane + 64], f2 = row[lane + 128];
        float s = f0.x*u0.x + f0.y*u0.y + f0.z*u0.z + f0.w*u0.w
                + f1.x*u1.x + f1.y*u1.y + f1.z*u1.z + f1.w*u1.w
                + f2.x*u2.x + f2.y*u2.y + f2.z*u2.z + f2.w*u2.w;
        if (lane < 4) {
            float4 f3 = row[192 + lane];
            s += f3.x*u3.x + f3.y*u3.y + f3.z*u3.z + f3.w*u3.w;
        }
        for (int off = 32; off; off >>= 1) s += __shfl_down(s, off, 64);
        if (lane == 0) {
            vb[c] = s;
            if (mode) { float xn = x2b[c] * rn2; p0 += s * xn; p1 += xn * xn; }
        }
    }
    if (mode && lane == 0) {
        atomicAdd(slot0, p0);
        atomicAdd(slot1, p1);
    }
}

__global__ __launch_bounds__(TPB, 4)
void c_all(const float* __restrict__ A, const float* __restrict__ x0,
           float* __restrict__ out, float* __restrict__ ws) {
    __shared__ float up[16][800];          // 51.2 KB
    __shared__ float red[16];
    cg::grid_group grid = cg::this_grid();

    float* acc  = ws;                      // 256 floats (64 x 4)
    float* ubuf = ws + 256;                // 6 x BB*DD
    float* tbuf = ws + 256 + 6 * BB * DD;  // 7 x BB*CC

    int b = blockIdx.x >> 2;
    int stripe = blockIdx.x & 3;
    int c0 = stripe * RPB;
    const float* Ab  = A + (size_t)b * CC * DD;
    const float* x0b = x0 + (size_t)b * CC;
    float* ub[6]; float* tb[7];
    for (int k = 0; k < 6; k++) ub[k] = ubuf + (size_t)k * BB * DD + (size_t)b * DD;
    for (int k = 0; k < 7; k++) tb[k] = tbuf + (size_t)k * BB * CC + (size_t)b * CC;
    // tb: 0..3 = t1..t4, 4 = t5 (AAT x1), 5 = y (unnorm x2), 6 = w

    // ---- zero atomic-accumulated storage (acc + u bufs)
    int ztot = 256 + 6 * BB * DD;
    for (int i = blockIdx.x * TPB + threadIdx.x; i < ztot; i += NBLK * TPB)
        ws[i] = 0.0f;
    grid.sync();

    // ---- 4 power steps: t_{k+1} = AAT * normalize(t_k)   (t_0 = x0)
    const float* xin = x0b;
    for (int k = 0; k < 4; k++) {
        float rn = 1.0f / fmaxf(sqrtf(ss512c(xin, red)), FEPS);
        c_phase_u(Ab, xin, rn, ub[k], c0, up);
        grid.sync();
        c_phase_v(Ab, ub[k], tb[k], c0, 0, nullptr, nullptr, nullptr, 0.f);
        grid.sync();
        xin = tb[k];
    }

    // ---- t5 = AAT x1, x1 = normalize(t4)
    {
        float rn4 = 1.0f / fmaxf(sqrtf(ss512c(tb[3], red)), FEPS);
        c_phase_u(Ab, tb[3], rn4, ub[4], c0, up);
        grid.sync();
        c_phase_v(Ab, ub[4], tb[4], c0, 0, nullptr, nullptr, nullptr, 0.f);
        grid.sync();
    }

    // ---- mid: largest = <t5,x1>/<x1,x1>; y = t5 - largest*x1
    {
        float rn4 = 1.0f / fmaxf(sqrtf(ss512c(tb[3], red)), FEPS);
        float a = (threadIdx.x < CC) ? tb[3][threadIdx.x] : 0.0f;
        float bv = (threadIdx.x < CC) ? tb[4][threadIdx.x] : 0.0f;
        float x1 = a * rn4;
        float num = blk_reduce16(bv * x1, red);
        float den = blk_reduce16(x1 * x1, red);
        float largest = num / den;
        if (threadIdx.x < RPB) {
            int c = c0 + threadIdx.x;
            tb[5][c] = tb[4][c] - largest * (tb[3][c] * rn4);
        }
        if (stripe == 0 && threadIdx.x == 0) acc[b * 4 + 0] = largest;
    }
    grid.sync();

    // ---- w = AAT x2, x2 = normalize(y); dotwx = <w,x2>, den2 = <x2,x2>
    {
        float rny = 1.0f / fmaxf(sqrtf(ss512c(tb[5], red)), FEPS);
        c_phase_u(Ab, tb[5], rny, ub[5], c0, up);
        grid.sync();
        c_phase_v(Ab, ub[5], tb[6], c0, 1, &acc[b * 4 + 1], &acc[b * 4 + 2],
                  tb[5], rny);
    }
    grid.sync();

    // ---- final: penalty = mean_b (largest/smallest - 1)^2
    if (blockIdx.x == 0 && threadIdx.x < 64) {
        int bb = threadIdx.x;
        float largest = acc[bb * 4 + 0];
        float dotwx   = acc[bb * 4 + 1];
        float den2    = acc[bb * 4 + 2];
        float tmp = (dotwx - largest * den2) / den2;
        float smallest = tmp + largest;
        float r = largest / smallest - 1.0f;
        float pen = r * r;                 // BETA = 1
        for (int off = 32; off; off >>= 1) pen += __shfl_down(pen, off, 64);
        if (bb == 0) out[0] = pen / (float)BB;
    }
}

// ======================= fallback: round-3 multi-launch =======================
#define STRIPES 16
#define RPS 32

__global__ void f_zero(float* __restrict__ p, int n) {
    int i = blockIdx.x * 256 + threadIdx.x;
    if (i < n) p[i] = 0.0f;
}

__device__ __forceinline__ float f_blk_reduce(float s, float* red) {
    for (int off = 32; off; off >>= 1) s += __shfl_down(s, off, 64);
    int w = threadIdx.x >> 6;
    if ((threadIdx.x & 63) == 0) red[w] = s;
    __syncthreads();
    float t = red[0] + red[1] + red[2] + red[3];
    __syncthreads();
    return t;
}

__global__ void f_init(const float* __restrict__ x0, float* __restrict__ acc) {
    __shared__ float red[4];
    int b = blockIdx.x;
    const float* x = x0 + (size_t)b * CC;
    float v0 = x[threadIdx.x], v1 = x[threadIdx.x + 256];
    float t = f_blk_reduce(v0 * v0 + v1 * v1, red);
    if (threadIdx.x == 0) acc[b * 16 + 0] = t;
}

__global__ __launch_bounds__(256, 4)
void f_u(const float* __restrict__ A, const float* __restrict__ xin,
         const float* __restrict__ acc, int ss_k, float* __restrict__ uout) {
    __shared__ float up[4][800];
    int b = blockIdx.y, stripe = blockIdx.x;
    int wave = threadIdx.x >> 6, lane = threadIdx.x & 63;
    int c0 = stripe * RPS;
    float rn = 1.0f / fmaxf(sqrtf(acc[b * 16 + ss_k]), FEPS);
    const float* xp = xin + (size_t)b * CC;
    float xv[8];
#pragma unroll
    for (int i = 0; i < 8; i++) xv[i] = xp[c0 + wave + 4 * i] * rn;
    const float4* Abase = (const float4*)(A + ((size_t)b * CC + c0) * DD);
    float4 a0 = make_float4(0.f,0.f,0.f,0.f), a1 = a0, a2 = a0, a3 = a0;
#pragma unroll 4
    for (int i = 0; i < 8; i++) {
        const float4* row = Abase + (size_t)(wave + 4 * i) * 196;
        float xc = xv[i];
        float4 f0 = row[lane], f1 = row[lane + 64], f2 = row[lane + 128];
        a0.x += f0.x*xc; a0.y += f0.y*xc; a0.z += f0.z*xc; a0.w += f0.w*xc;
        a1.x += f1.x*xc; a1.y += f1.y*xc; a1.z += f1.z*xc; a1.w += f1.w*xc;
        a2.x += f2.x*xc; a2.y += f2.y*xc; a2.z += f2.z*xc; a2.w += f2.w*xc;
        if (lane < 4) {
            float4 f3 = row[192 + lane];
            a3.x += f3.x*xc; a3.y += f3.y*xc; a3.z += f3.z*xc; a3.w += f3.w*xc;
        }
    }
    int d4 = 4 * lane;
    *(float4*)&up[wave][d4]       = a0;
    *(float4*)&up[wave][d4 + 256] = a1;
    *(float4*)&up[wave][d4 + 512] = a2;
    if (lane < 4) *(float4*)&up[wave][d4 + 768] = a3;
    __syncthreads();
    float* uo = uout + (size_t)b * DD;
    for (int d = threadIdx.x; d < DD; d += 256)
        atomicAdd(&uo[d], up[0][d] + up[1][d] + up[2][d] + up[3][d]);
}

__global__ void f_a(const float* __restrict__ A, const float* __restrict__ u,
                    float* __restrict__ vout, float* __restrict__ acc,
                    int mode, int k0,
                    const float* __restrict__ xvec2, int ss_k2) {
    int b = blockIdx.y;
    int wave = threadIdx.x >> 6, lane = threadIdx.x & 63;
    int c = blockIdx.x * 4 + wave;
    const float4* ap = (const float4*)(A + (size_t)(b * CC + c) * DD);
    const float4* up = (const float4*)(u + (size_t)b * DD);
    float s = 0.0f;
#pragma unroll
    for (int k = 0; k < 3; ++k) {
        float4 a4 = ap[lane + 64 * k];
        float4 u4 = up[lane + 64 * k];
        s += a4.x*u4.x + a4.y*u4.y + a4.z*u4.z + a4.w*u4.w;
    }
    if (lane < 4) {
        float4 a4 = ap[192 + lane];
        float4 u4 = up[192 + lane];
        s += a4.x*u4.x + a4.y*u4.y + a4.z*u4.z + a4.w*u4.w;
    }
    for (int off = 32; off; off >>= 1) s += __shfl_down(s, off, 64);
    __shared__ float p0[4], p1[4];
    if (lane == 0) {
        if (vout) vout[(size_t)b * CC + c] = s;
        if (mode == 0) { p0[wave] = s * s; p1[wave] = 0.0f; }
        else {
            float denom2 = fmaxf(sqrtf(acc[b * 16 + ss_k2]), FEPS);
            float xn = xvec2[(size_t)b * CC + c] / denom2;
            p0[wave] = s * xn; p1[wave] = xn * xn;
        }
    }
    __syncthreads();
    if (threadIdx.x == 0) {
        atomicAdd(&acc[b * 16 + k0], p0[0] + p0[1] + p0[2] + p0[3]);
        if (mode == 1)
            atomicAdd(&acc[b * 16 + k0 + 1], p1[0] + p1[1] + p1[2] + p1[3]);
    }
}

__global__ void f_mid(const float* __restrict__ t4, const float* __restrict__ t5,
                      float* __restrict__ acc, float* __restrict__ y) {
    __shared__ float red[4];
    int b = blockIdx.x;
    float num = acc[b * 16 + 5], den = acc[b * 16 + 6];
    float largest = num / den;
    float rn = 1.0f / fmaxf(sqrtf(acc[b * 16 + 4]), FEPS);
    const float* p4 = t4 + (size_t)b * CC;
    const float* p5 = t5 + (size_t)b * CC;
    float* yp = y + (size_t)b * CC;
    float a0 = p4[threadIdx.x], a1 = p4[threadIdx.x + 256];
    float b0 = p5[threadIdx.x], b1 = p5[threadIdx.x + 256];
    float y0 = b0 - largest * (a0 * rn);
    float y1 = b1 - largest * (a1 * rn);
    yp[threadIdx.x] = y0;
    yp[threadIdx.x + 256] = y1;
    float t = f_blk_reduce(y0 * y0 + y1 * y1, red);
    if (threadIdx.x == 0) { acc[b * 16 + 7] = t; acc[b * 16 + 8] = largest; }
}

__global__ void f_out(const float* __restrict__ acc, float* __restrict__ out) {
    int b = threadIdx.x;
    float largest = acc[b * 16 + 8];
    float dotwx   = acc[b * 16 + 9];
    float den2    = acc[b * 16 + 10];
    float tmp = (dotwx - largest * den2) / den2;
    float smallest = tmp + largest;
    float r = largest / smallest - 1.0f;
    float pen = r * r;
    for (int off = 32; off; off >>= 1) pen += __shfl_down(pen, off, 64);
    if (b == 0) out[0] = pen / (float)BB;
}

extern "C" void kernel_launch(void* const* d_in, const int* in_sizes, int n_in,
                              void* d_out, int out_size, void* d_ws, size_t ws_size,
                              hipStream_t stream) {
    const float* A  = (const float*)d_in[0];
    const float* x0 = (const float*)d_in[1];
    float* out = (float*)d_out;
    float* ws  = (float*)d_ws;

    void* args[] = { (void*)&A, (void*)&x0, (void*)&out, (void*)&ws };
    hipError_t e = hipLaunchCooperativeKernel((const void*)c_all, dim3(NBLK),
                                              dim3(TPB), args, 0, stream);
    if (e == hipSuccess) return;

    // ---------- fallback: proven round-3 multi-launch path ----------
    float* acc = ws;
    float* u1  = ws + 1024;
    float* u2  = u1 + BB * DD;
    float* u3  = u2 + BB * DD;
    float* u4  = u3 + BB * DD;
    float* u5  = u4 + BB * DD;
    float* u6  = u5 + BB * DD;
    float* t1  = u6 + BB * DD;
    float* t2  = t1 + BB * CC;
    float* t3  = t2 + BB * CC;
    float* t4  = t3 + BB * CC;
    float* t5  = t4 + BB * CC;
    float* y   = t5 + BB * CC;

    int nz = 1024 + 6 * BB * DD;
    f_zero<<<(nz + 255) / 256, 256, 0, stream>>>(ws, nz);
    f_init<<<BB, 256, 0, stream>>>(x0, acc);

    dim3 gU(STRIPES, BB), gA(CC / 4, BB);
    f_u<<<gU, 256, 0, stream>>>(A, x0, acc, 0, u1);
    f_a<<<gA, 256, 0, stream>>>(A, u1, t1, acc, 0, 1, nullptr, 0);
    f_u<<<gU, 256, 0, stream>>>(A, t1, acc, 1, u2);
    f_a<<<gA, 256, 0, stream>>>(A, u2, t2, acc, 0, 2, nullptr, 0);
    f_u<<<gU, 256, 0, stream>>>(A, t2, acc, 2, u3);
    f_a<<<gA, 256, 0, stream>>>(A, u3, t3, acc, 0, 3, nullptr, 0);
    f_u<<<gU, 256, 0, stream>>>(A, t3, acc, 3, u4);
    f_a<<<gA, 256, 0, stream>>>(A, u4, t4, acc, 0, 4, nullptr, 0);
    f_u<<<gU, 256, 0, stream>>>(A, t4, acc, 4, u5);
    f_a<<<gA, 256, 0, stream>>>(A, u5, t5, acc, 1, 5, t4, 4);
    f_mid<<<BB, 256, 0, stream>>>(t4, t5, acc, y);
    f_u<<<gU, 256, 0, stream>>>(A, y, acc, 7, u6);
    f_a<<<gA, 256, 0, stream>>>(A, u6, nullptr, acc, 1, 9, y, 7);
    f_out<<<1, 64, 0, stream>>>(acc, out);
}